// Round 8
// baseline (288.645 us; speedup 1.0000x reference)
//
#include <hip/hip_runtime.h>
#include <hip/hip_bf16.h>
#include <stdint.h>

// Problem constants: B=8, N=4096, C=512, K=V=512, H=8, hk=hv=64, M = B*N = 32768

typedef __attribute__((ext_vector_type(8))) short short8;
typedef __attribute__((ext_vector_type(4))) float f32x4;
typedef __attribute__((ext_vector_type(4))) unsigned short us4;

__device__ __forceinline__ unsigned short f2bf(float f) {
  union { float f; unsigned u; } v; v.f = f;
  unsigned r = v.u + 0x7FFFu + ((v.u >> 16) & 1u);  // RNE
  return (unsigned short)(r >> 16);
}
__device__ __forceinline__ float bf2f(unsigned short u) {
  union { unsigned u; float f; } v; v.u = ((unsigned)u) << 16;
  return v.f;
}
__device__ __forceinline__ ushort2 pk2(float a, float b) {
  __hip_bfloat162 h = __float22bfloat162_rn(float2{a, b});
  return *reinterpret_cast<ushort2*>(&h);
}
// async global->LDS, 16B per lane; lds base wave-uniform (HW: base + lane*16)
__device__ __forceinline__ void gload16(const void* g, void* l) {
  __builtin_amdgcn_global_load_lds(
      (const __attribute__((address_space(1))) void*)g,
      (__attribute__((address_space(3))) void*)l, 16, 0, 0);
}

// ---------------------------------------------------------------------------
// Transpose + bf16-convert the 4 weight matrices: Wt[w][out][in] = W[in][out]
__global__ void prep_w(const float* __restrict__ Wk, const float* __restrict__ Wq,
                       const float* __restrict__ Wv, const float* __restrict__ Wr,
                       unsigned short* __restrict__ Wt) {
  __shared__ float tile[64][65];
  const int t = threadIdx.x;
  const int bx = blockIdx.x, by = blockIdx.y, w = blockIdx.z;
  const float* W = (w == 0) ? Wk : (w == 1) ? Wq : (w == 2) ? Wv : Wr;
  unsigned short* O = Wt + (size_t)w * 512 * 512;
#pragma unroll
  for (int p = 0; p < 16; ++p) {
    int idx = p * 256 + t; int r = idx >> 6, c = idx & 63;
    tile[r][c] = W[(size_t)(by * 64 + r) * 512 + bx * 64 + c];
  }
  __syncthreads();
#pragma unroll
  for (int p = 0; p < 16; ++p) {
    int idx = p * 256 + t; int r = idx >> 6, c = idx & 63;
    O[(size_t)(bx * 64 + r) * 512 + by * 64 + c] = f2bf(tile[c][r]);
  }
}

// ---------------------------------------------------------------------------
// Projection GEMM with fp32 A (in-kernel cvt, T14 async-split reg-staging) and
// bf16 B via global_load_lds. 128x128 tile, BK=64, double-buffered LDS,
// counted vmcnt, raw s_barrier, XOR-swizzled LDS on both operands.
// MODE 0: A = x + y (fp32 sum), epilogue exp(), TRANSPOSED out + S atomics
// MODE 1: A = y, epilogue fused head-softmax (64 ch), row-major bf16 out
// MODE 2: A = x, plain, TRANSPOSED out
template <int MODE>
__global__ __launch_bounds__(256) void gemm_projf(
    const float* __restrict__ A0, const float* __restrict__ A1,
    const unsigned short* __restrict__ Bt, const float* __restrict__ bias,
    unsigned short* __restrict__ Out, float* __restrict__ S) {
  __shared__ __align__(16) unsigned short As[2][128][64];
  __shared__ __align__(16) unsigned short Bs[2][128][64];
  const int t = threadIdx.x, l = t & 63, w = t >> 6;
  const int lr = l & 15, lg = l >> 4;
  const int wr = w >> 1, wc = w & 1;
  const int bid = blockIdx.x;
  const int swz = (bid & 7) * 128 + (bid >> 3);  // bijective XCD swizzle (1024 % 8 == 0)
  const int tn = swz & 3, tm = swz >> 2;

  // B staging geometry (gload_lds, pre-swizzled global source)  [G21]
  const int r0 = w * 8 + (l >> 3);
  const int su = ((l & 7) ^ (l >> 3)) * 8;
  const unsigned short* Bg = Bt + (size_t)(tn * 128 + r0) * 512 + su;

  // A reg-staging geometry: 2 threads/row, 32 fp32 each (4 16B-units of 8 shorts)
  const int ar = t >> 1, ah = t & 1;
  const float* Ar0 = A0 + (size_t)(tm * 128 + ar) * 512 + ah * 32;
  const float* Ar1 = (MODE == 0) ? (A1 + (size_t)(tm * 128 + ar) * 512 + ah * 32) : nullptr;

  float4 ax[8], ay[8];
  f32x4 acc[4][4] = {};

#define FENCE asm volatile("" ::: "memory")
#define ALOAD(kt)                                                              \
  {                                                                            \
    _Pragma("unroll") for (int i = 0; i < 8; ++i)                              \
        ax[i] = *(const float4*)(Ar0 + (kt) * 64 + i * 4);                     \
    if (MODE == 0) {                                                           \
      _Pragma("unroll") for (int i = 0; i < 8; ++i)                            \
          ay[i] = *(const float4*)(Ar1 + (kt) * 64 + i * 4);                   \
    }                                                                          \
  }
#define AWRITE(buf)                                                            \
  {                                                                            \
    _Pragma("unroll") for (int iu = 0; iu < 4; ++iu) {                         \
      float4 u0 = ax[2 * iu], u1 = ax[2 * iu + 1];                             \
      if (MODE == 0) {                                                         \
        float4 v0 = ay[2 * iu], v1 = ay[2 * iu + 1];                           \
        u0.x += v0.x; u0.y += v0.y; u0.z += v0.z; u0.w += v0.w;                \
        u1.x += v1.x; u1.y += v1.y; u1.z += v1.z; u1.w += v1.w;                \
      }                                                                        \
      ushort2 c0 = pk2(u0.x, u0.y), c1 = pk2(u0.z, u0.w);                      \
      ushort2 c2 = pk2(u1.x, u1.y), c3 = pk2(u1.z, u1.w);                      \
      short8 v;                                                                \
      v[0] = (short)c0.x; v[1] = (short)c0.y; v[2] = (short)c1.x;              \
      v[3] = (short)c1.y; v[4] = (short)c2.x; v[5] = (short)c2.y;              \
      v[6] = (short)c3.x; v[7] = (short)c3.y;                                  \
      *(short8*)&As[buf][ar][(((ah * 4 + iu) ^ (ar & 7)) * 8)] = v;            \
    }                                                                          \
  }
#define BGISS(buf, kt)                                                         \
  {                                                                            \
    _Pragma("unroll") for (int i = 0; i < 4; ++i)                              \
        gload16(Bg + (size_t)i * 32 * 512 + (kt) * 64, &Bs[buf][i * 32 + w * 8][0]); \
  }
#define WAIT_A asm volatile("s_waitcnt vmcnt(4)" ::: "memory")
#define WAIT_B                                                                 \
  {                                                                            \
    if (MODE == 0) { asm volatile("s_waitcnt vmcnt(24)" ::: "memory"); }       \
    else           { asm volatile("s_waitcnt vmcnt(16)" ::: "memory"); }       \
  }
  // note: WAIT_B count = AN + 8 where AN = 16 (MODE 0) or 8

  // ---- prologue: stage tile 0, issue tile 1 ----
  ALOAD(0); FENCE; BGISS(0, 0);
  WAIT_A;                     // A(0) regs ready (4 B gloads may remain)
  AWRITE(0);
  FENCE; ALOAD(1); FENCE; BGISS(1, 1);
  asm volatile("s_waitcnt lgkmcnt(0)" ::: "memory");
  WAIT_B;                     // B(0) landed; A(1)+B(1) stay in flight
  __builtin_amdgcn_s_barrier();
  FENCE;

  // ---- main loop ----
  for (int kt = 0; kt < 8; ++kt) {
    const int cur = kt & 1;
    __builtin_amdgcn_s_setprio(1);
#pragma unroll
    for (int kk = 0; kk < 2; ++kk) {
      short8 af[4], bf[4];
#pragma unroll
      for (int m = 0; m < 4; ++m)
        af[m] = *(const short8*)&As[cur][wr * 64 + m * 16 + lr][((kk * 4 + lg) ^ (lr & 7)) * 8];
#pragma unroll
      for (int n = 0; n < 4; ++n)
        bf[n] = *(const short8*)&Bs[cur][wc * 64 + n * 16 + lr][((kk * 4 + lg) ^ (lr & 7)) * 8];
#pragma unroll
      for (int m = 0; m < 4; ++m)
#pragma unroll
        for (int n = 0; n < 4; ++n)
          acc[m][n] = __builtin_amdgcn_mfma_f32_16x16x32_bf16(af[m], bf[n], acc[m][n], 0, 0, 0);
    }
    __builtin_amdgcn_s_setprio(0);
    FENCE;
    if (kt < 7) {
      WAIT_A;                 // A(kt+1) regs ready
      AWRITE(cur ^ 1);        // tile kt+1 A -> nxt buffer
      asm volatile("s_waitcnt lgkmcnt(0)" ::: "memory");
      __builtin_amdgcn_s_barrier();  // #1: releases buf cur; A(kt+1) writes visible
      FENCE;
      if (kt < 6) {
        ALOAD(kt + 2); FENCE; BGISS(cur, kt + 2);
        WAIT_B;               // B(kt+1) landed; tile kt+2 stays in flight
      } else {
        asm volatile("s_waitcnt vmcnt(0)" ::: "memory");  // drain B(7)
      }
      __builtin_amdgcn_s_barrier();  // #2: tile kt+1 fully staged for all waves
      FENCE;
    }
  }
  asm volatile("s_waitcnt vmcnt(0) lgkmcnt(0)" ::: "memory");
#undef FENCE
#undef ALOAD
#undef AWRITE
#undef BGISS
#undef WAIT_A
#undef WAIT_B

  // ---- epilogue ----
  const int c_base = tn * 128 + wc * 64;
  const int r_base = tm * 128 + wr * 64;
  float bv_[4];
#pragma unroll
  for (int n = 0; n < 4; ++n) bv_[n] = bias[c_base + n * 16 + lr];

  if (MODE == 1) {
    // fused query-softmax over this wave's 64 cols (= one head), fp32 in-register
#pragma unroll
    for (int m = 0; m < 4; ++m) {
#pragma unroll
      for (int j = 0; j < 4; ++j) {
        float a0 = acc[m][0][j] + bv_[0], a1 = acc[m][1][j] + bv_[1];
        float a2 = acc[m][2][j] + bv_[2], a3 = acc[m][3][j] + bv_[3];
        float mx = fmaxf(fmaxf(a0, a1), fmaxf(a2, a3));
#pragma unroll
        for (int o = 1; o < 16; o <<= 1) mx = fmaxf(mx, __shfl_xor(mx, o));
        float e0 = __expf(a0 - mx), e1 = __expf(a1 - mx);
        float e2 = __expf(a2 - mx), e3 = __expf(a3 - mx);
        float s = e0 + e1 + e2 + e3;
#pragma unroll
        for (int o = 1; o < 16; o <<= 1) s += __shfl_xor(s, o);
        const float rs = 1.0f / s;
        const int row = r_base + m * 16 + lg * 4 + j;
        Out[(size_t)row * 512 + c_base + 0 * 16 + lr] = f2bf(e0 * rs);
        Out[(size_t)row * 512 + c_base + 1 * 16 + lr] = f2bf(e1 * rs);
        Out[(size_t)row * 512 + c_base + 2 * 16 + lr] = f2bf(e2 * rs);
        Out[(size_t)row * 512 + c_base + 3 * 16 + lr] = f2bf(e3 * rs);
      }
    }
  } else if (MODE == 0) {
    const int b = (tm * 128) >> 12;  // tile rows never cross a batch
#pragma unroll
    for (int n = 0; n < 4; ++n) {
      const int col = c_base + n * 16 + lr;
      float srow = 0.f;
#pragma unroll
      for (int m = 0; m < 4; ++m) {
        const int row = r_base + m * 16 + lg * 4;
        const int nl = row & 4095;
        us4 v;
#pragma unroll
        for (int j = 0; j < 4; ++j) {
          float f = __expf(acc[m][n][j] + bv_[n]);
          srow += f;
          v[j] = f2bf(f);
        }
        *(us4*)&Out[((size_t)(b * 512 + col)) * 4096 + nl] = v;
      }
      srow += __shfl_xor(srow, 16);
      srow += __shfl_xor(srow, 32);
      if (lg == 0) atomicAdd(&S[b * 512 + col], srow);
    }
  } else {
    const int b = (tm * 128) >> 12;
#pragma unroll
    for (int n = 0; n < 4; ++n) {
      const int col = c_base + n * 16 + lr;
#pragma unroll
      for (int m = 0; m < 4; ++m) {
        const int row = r_base + m * 16 + lg * 4;
        const int nl = row & 4095;
        us4 v;
#pragma unroll
        for (int j = 0; j < 4; ++j) v[j] = f2bf(acc[m][n][j] + bv_[n]);
        *(us4*)&Out[((size_t)(b * 512 + col)) * 4096 + nl] = v;
      }
    }
  }
}

// ---------------------------------------------------------------------------
// Final GEMM (R5 skeleton, pure bf16 gload path):
// out[tok][c] = sum_j Qs[tok][j] * MT[b][c][j] + br[c]  (fp32 out)
__global__ __launch_bounds__(256) void gemm_final(const unsigned short* __restrict__ Qs,
                           const unsigned short* __restrict__ MT,
                           const float* __restrict__ br, float* __restrict__ out) {
  __shared__ __align__(16) unsigned short As[2][128][64];
  __shared__ __align__(16) unsigned short Bs[2][128][64];
  const int t = threadIdx.x, l = t & 63, w = t >> 6;
  const int lr = l & 15, lg = l >> 4;
  const int wr = w >> 1, wc = w & 1;
  const int bid = blockIdx.x;
  const int swz = (bid & 7) * 128 + (bid >> 3);
  const int tn = swz & 3, tm = swz >> 2;

  const unsigned short* Bbase = MT + (size_t)(tm >> 5) * 262144;
  const int r0 = w * 8 + (l >> 3);
  const int su = ((l & 7) ^ (l >> 3)) * 8;
  const unsigned short* Ag = Qs + (size_t)(tm * 128 + r0) * 512 + su;
  const unsigned short* Bg = Bbase + (size_t)(tn * 128 + r0) * 512 + su;

  f32x4 acc[4][4] = {};

#define PSTAGE(buf, kt)                                                        \
  {                                                                            \
    _Pragma("unroll") for (int i = 0; i < 4; ++i) {                            \
      gload16(Ag + (size_t)i * 32 * 512 + (kt) * 64, &As[buf][i * 32 + w * 8][0]); \
      gload16(Bg + (size_t)i * 32 * 512 + (kt) * 64, &Bs[buf][i * 32 + w * 8][0]); \
    }                                                                          \
  }

  PSTAGE(0, 0)
  PSTAGE(1, 1)
  for (int kt = 0; kt < 8; ++kt) {
    const int cur = kt & 1;
    if (kt < 7) { asm volatile("s_waitcnt vmcnt(8)" ::: "memory"); }
    else        { asm volatile("s_waitcnt vmcnt(0)" ::: "memory"); }
    __builtin_amdgcn_s_barrier();
    asm volatile("" ::: "memory");
    __builtin_amdgcn_s_setprio(1);
#pragma unroll
    for (int kk = 0; kk < 2; ++kk) {
      short8 af[4], bf[4];
#pragma unroll
      for (int m = 0; m < 4; ++m)
        af[m] = *(const short8*)&As[cur][wr * 64 + m * 16 + lr][((kk * 4 + lg) ^ (lr & 7)) * 8];
#pragma unroll
      for (int n = 0; n < 4; ++n)
        bf[n] = *(const short8*)&Bs[cur][wc * 64 + n * 16 + lr][((kk * 4 + lg) ^ (lr & 7)) * 8];
#pragma unroll
      for (int m = 0; m < 4; ++m)
#pragma unroll
        for (int n = 0; n < 4; ++n)
          acc[m][n] = __builtin_amdgcn_mfma_f32_16x16x32_bf16(af[m], bf[n], acc[m][n], 0, 0, 0);
    }
    __builtin_amdgcn_s_setprio(0);
    asm volatile("" ::: "memory");
    __builtin_amdgcn_s_barrier();
    asm volatile("" ::: "memory");
    if (kt < 6) PSTAGE(cur, kt + 2)
  }
#undef PSTAGE

  const int c_base = tn * 128 + wc * 64;
  const int r_base = tm * 128 + wr * 64;
#pragma unroll
  for (int n = 0; n < 4; ++n) {
    const int col = c_base + n * 16 + lr;
    const float bs = br[col];
#pragma unroll
    for (int m = 0; m < 4; ++m) {
      const int row = r_base + m * 16 + lg * 4;
#pragma unroll
      for (int j = 0; j < 4; ++j)
        out[(size_t)(row + j) * 512 + col] = acc[m][n][j] + bs;
    }
  }
}

// ---------------------------------------------------------------------------
// Partial context: D[v][k] = sum_tok VT[v][tok] * KeT[k][tok] over a 1024-token chunk.
__global__ void context_partial(const unsigned short* __restrict__ KeT,
                                const unsigned short* __restrict__ VT,
                                float* __restrict__ cp) {
  const int t = threadIdx.x, l = t & 63, w = t >> 6;
  const int lr = l & 15, lg = l >> 4;
  const int ch = blockIdx.x, h = blockIdx.y, b = blockIdx.z;
  const unsigned short* Kp = KeT + ((size_t)b * 512 + h * 64) * 4096;
  const unsigned short* Vp = VT + ((size_t)b * 512 + h * 64) * 4096;
  const int tok_w = ch * 1024 + w * 256;
  f32x4 acc[4][4] = {};
  for (int s = 0; s < 8; ++s) {
    const int tok = tok_w + s * 32 + lg * 8;
    short8 a[4], kf[4];
#pragma unroll
    for (int m = 0; m < 4; ++m) a[m] = *(const short8*)&Vp[(size_t)(m * 16 + lr) * 4096 + tok];
#pragma unroll
    for (int n = 0; n < 4; ++n) kf[n] = *(const short8*)&Kp[(size_t)(n * 16 + lr) * 4096 + tok];
#pragma unroll
    for (int m = 0; m < 4; ++m)
#pragma unroll
      for (int n = 0; n < 4; ++n)
        acc[m][n] = __builtin_amdgcn_mfma_f32_16x16x32_bf16(a[m], kf[n], acc[m][n], 0, 0, 0);
  }
  __shared__ float red[4][64][64];
#pragma unroll
  for (int m = 0; m < 4; ++m)
#pragma unroll
    for (int n = 0; n < 4; ++n)
#pragma unroll
      for (int j = 0; j < 4; ++j)
        red[w][m * 16 + lg * 4 + j][n * 16 + lr] = acc[m][n][j];
  __syncthreads();
  const int blk = (b * 8 + h) * 4 + ch;
  float* o = cp + (size_t)blk * 4096;
  for (int i = 0; i < 16; ++i) {
    int e = i * 256 + t;
    int v = e >> 6, k = e & 63;
    o[e] = red[0][v][k] + red[1][v][k] + red[2][v][k] + red[3][v][k];
  }
}

// Reduce 4 chunk-partials, normalize by S, store transposed: ctxN[bh][k][v] (bf16)
__global__ void ctx_reduce(const float* __restrict__ cp, const float* __restrict__ S,
                           unsigned short* __restrict__ ctxN) {
  const int bh = blockIdx.x, t = threadIdx.x;
  const float* p = cp + (size_t)bh * 4 * 4096;
  for (int i = 0; i < 16; ++i) {
    int e = i * 256 + t;
    float vsum = p[e] + p[4096 + e] + p[8192 + e] + p[12288 + e];
    int v = e >> 6, k = e & 63;
    ctxN[(size_t)bh * 4096 + k * 64 + v] = f2bf(vsum / S[bh * 64 + k]);
  }
}

// ---------------------------------------------------------------------------
// M[b][c][h*64+k] = sum_v ctxN[b,h][k][v] * Wr[h*64+v][c]   (transposed for final GEMM)
__global__ void ctx_mm(const unsigned short* __restrict__ ctxN, const unsigned short* __restrict__ Wrt,
                       unsigned short* __restrict__ MT) {
  const int t = threadIdx.x, l = t & 63, w = t >> 6;
  const int lr = l & 15, lg = l >> 4;
  const int h = blockIdx.x, b = blockIdx.y;
  const unsigned short* Ap = ctxN + (size_t)(b * 8 + h) * 4096;
  f32x4 acc[4][8] = {};
  const int c0 = w * 128;
#pragma unroll
  for (int kk = 0; kk < 2; ++kk) {
    const int vb = kk * 32 + lg * 8;
    short8 a[4], bfr[8];
#pragma unroll
    for (int m = 0; m < 4; ++m) a[m] = *(const short8*)&Ap[(m * 16 + lr) * 64 + vb];
#pragma unroll
    for (int n = 0; n < 8; ++n) bfr[n] = *(const short8*)&Wrt[(size_t)(c0 + n * 16 + lr) * 512 + h * 64 + vb];
#pragma unroll
    for (int m = 0; m < 4; ++m)
#pragma unroll
      for (int n = 0; n < 8; ++n)
        acc[m][n] = __builtin_amdgcn_mfma_f32_16x16x32_bf16(a[m], bfr[n], acc[m][n], 0, 0, 0);
  }
#pragma unroll
  for (int n = 0; n < 8; ++n) {
    const int c = c0 + n * 16 + lr;
#pragma unroll
    for (int m = 0; m < 4; ++m) {
      const int k = m * 16 + lg * 4;
      us4 v;
#pragma unroll
      for (int j = 0; j < 4; ++j) v[j] = f2bf(acc[m][n][j]);
      *(us4*)&MT[((size_t)b * 512 + c) * 512 + h * 64 + k] = v;
    }
  }
}

// ---------------------------------------------------------------------------
extern "C" void kernel_launch(void* const* d_in, const int* in_sizes, int n_in,
                              void* d_out, int out_size, void* d_ws, size_t ws_size,
                              hipStream_t stream) {
  (void)in_sizes; (void)n_in; (void)out_size; (void)ws_size;
  const float* x  = (const float*)d_in[0];
  const float* y  = (const float*)d_in[1];
  const float* Wk = (const float*)d_in[2];
  const float* bk = (const float*)d_in[3];
  const float* Wq = (const float*)d_in[4];
  const float* bq = (const float*)d_in[5];
  const float* Wv = (const float*)d_in[6];
  const float* bv = (const float*)d_in[7];
  const float* Wr = (const float*)d_in[8];
  const float* br = (const float*)d_in[9];
  float* out = (float*)d_out;

  char* ws = (char*)d_ws;
  unsigned short* Wt   = (unsigned short*)(ws + 0);            //   2 MB: 4x [512][512] bf16
  unsigned short* KeT  = (unsigned short*)(ws + 2097152);      //  32 MB: [B][512][4096] bf16
  unsigned short* VT   = (unsigned short*)(ws + 35651584);     //  32 MB: [B][512][4096] bf16
  unsigned short* Qp   = (unsigned short*)(ws + 69206016);     //  32 MB: [32768][512] bf16
  float* S             = (float*)(ws + 102760448);             //  16 KB
  float* cp            = (float*)(ws + 102776832);             //   4 MB
  unsigned short* ctxN = (unsigned short*)(ws + 106971136);    //  .5 MB
  unsigned short* MT   = (unsigned short*)(ws + 107495424);    //   4 MB (ends ~111.5 MB)

  prep_w<<<dim3(8, 8, 4), 256, 0, stream>>>(Wk, Wq, Wv, Wr, Wt);
  hipMemsetAsync(S, 0, 512 * 8 * sizeof(float), stream);
  gemm_projf<0><<<1024, 256, 0, stream>>>(x, y, Wt, bk, KeT, S);
  gemm_projf<2><<<1024, 256, 0, stream>>>(x, nullptr, Wt + 2 * 262144, bv, VT, nullptr);
  gemm_projf<1><<<1024, 256, 0, stream>>>(y, nullptr, Wt + 262144, bq, Qp, nullptr);
  context_partial<<<dim3(4, 8, 8), 256, 0, stream>>>(KeT, VT, cp);
  ctx_reduce<<<64, 256, 0, stream>>>(cp, S, ctxN);
  ctx_mm<<<dim3(8, 8), 256, 0, stream>>>(ctxN, Wt + 3 * 262144, MT);
  gemm_final<<<1024, 256, 0, stream>>>(Qp, MT, br, out);
}

// Round 9
// 187.698 us; speedup vs baseline: 1.5378x; 1.5378x over previous
//
#include <hip/hip_runtime.h>
#include <hip/hip_bf16.h>
#include <stdint.h>

// Problem constants: B=8, N=4096, C=512, K=V=512, H=8, hk=hv=64, M = B*N = 32768

typedef __attribute__((ext_vector_type(8))) short short8;
typedef __attribute__((ext_vector_type(4))) float f32x4;
typedef __attribute__((ext_vector_type(4))) unsigned short us4;

__device__ __forceinline__ unsigned short f2bf(float f) {
  union { float f; unsigned u; } v; v.f = f;
  unsigned r = v.u + 0x7FFFu + ((v.u >> 16) & 1u);  // RNE
  return (unsigned short)(r >> 16);
}
__device__ __forceinline__ float bf2f(unsigned short u) {
  union { unsigned u; float f; } v; v.u = ((unsigned)u) << 16;
  return v.f;
}
__device__ __forceinline__ ushort2 pk2(float a, float b) {
  __hip_bfloat162 h = __float22bfloat162_rn(float2{a, b});
  return *reinterpret_cast<ushort2*>(&h);
}
__device__ __forceinline__ us4 cvt4(float4 a) {
  ushort2 c0 = pk2(a.x, a.y), c1 = pk2(a.z, a.w);
  us4 r; r[0] = c0.x; r[1] = c0.y; r[2] = c1.x; r[3] = c1.y;
  return r;
}
// async global->LDS, 16B per lane; lds base wave-uniform (HW: base + lane*16)
__device__ __forceinline__ void gload16(const void* g, void* l) {
  __builtin_amdgcn_global_load_lds(
      (const __attribute__((address_space(1))) void*)g,
      (__attribute__((address_space(3))) void*)l, 16, 0, 0);
}

// ---------------------------------------------------------------------------
// Transpose + bf16-convert the 4 weight matrices: Wt[w][out][in] = W[in][out]
__global__ void prep_w(const float* __restrict__ Wk, const float* __restrict__ Wq,
                       const float* __restrict__ Wv, const float* __restrict__ Wr,
                       unsigned short* __restrict__ Wt) {
  __shared__ float tile[64][65];
  const int t = threadIdx.x;
  const int bx = blockIdx.x, by = blockIdx.y, w = blockIdx.z;
  const float* W = (w == 0) ? Wk : (w == 1) ? Wq : (w == 2) ? Wv : Wr;
  unsigned short* O = Wt + (size_t)w * 512 * 512;
#pragma unroll
  for (int p = 0; p < 16; ++p) {
    int idx = p * 256 + t; int r = idx >> 6, c = idx & 63;
    tile[r][c] = W[(size_t)(by * 64 + r) * 512 + bx * 64 + c];
  }
  __syncthreads();
#pragma unroll
  for (int p = 0; p < 16; ++p) {
    int idx = p * 256 + t; int r = idx >> 6, c = idx & 63;
    O[(size_t)(bx * 64 + r) * 512 + by * 64 + c] = f2bf(tile[c][r]);
  }
}

// ---------------------------------------------------------------------------
// Streaming pre-pass: xb=bf16(x), yb=bf16(y), xyb=bf16(x+y).
// Fully coalesced: float4 loads (16B/lane) and ushort4 stores (8B/lane),
// two 1024-float panels per 256-thread block.
__global__ __launch_bounds__(256) void prep_xy(const float* __restrict__ x, const float* __restrict__ y,
                        unsigned short* __restrict__ xb, unsigned short* __restrict__ yb,
                        unsigned short* __restrict__ xyb) {
  const size_t base = (size_t)blockIdx.x * 2048;
  const int t = threadIdx.x;
  const size_t i1 = base + t * 4, i2 = base + 1024 + t * 4;
  float4 x1 = *(const float4*)(x + i1);
  float4 x2 = *(const float4*)(x + i2);
  float4 y1 = *(const float4*)(y + i1);
  float4 y2 = *(const float4*)(y + i2);
  float4 s1{x1.x + y1.x, x1.y + y1.y, x1.z + y1.z, x1.w + y1.w};
  float4 s2{x2.x + y2.x, x2.y + y2.y, x2.z + y2.z, x2.w + y2.w};
  *(us4*)(xb + i1) = cvt4(x1);
  *(us4*)(xb + i2) = cvt4(x2);
  *(us4*)(yb + i1) = cvt4(y1);
  *(us4*)(yb + i2) = cvt4(y2);
  *(us4*)(xyb + i1) = cvt4(s1);
  *(us4*)(xyb + i2) = cvt4(s2);
}

// ---------------------------------------------------------------------------
// bf16 GEMM (R5 skeleton, proven ~25us): 128x128 tile, BK=64, double-buffered
// LDS, counted vmcnt (never 0 mid-loop), raw s_barrier, XOR-swizzled LDS
// (linear gload dest + pre-swizzled global src, swizzled ds_read).
// MODE 0: epilogue exp(), TRANSPOSED out (KeT[b][k][tok]) + S atomic row-sums
// MODE 1: epilogue fused head-softmax (64 ch), row-major bf16 out
// MODE 2: plain, TRANSPOSED out (VT[b][v][tok], bf16)
// MODE 3: final: B = Bmat + batch*512*512, fp32 row-major out + bias
template <int MODE>
__global__ __launch_bounds__(256) void gemm_bf16(const unsigned short* __restrict__ A,
                          const unsigned short* __restrict__ Bmat,
                          const float* __restrict__ bias, void* __restrict__ OutV,
                          float* __restrict__ S) {
  __shared__ __align__(16) unsigned short As[2][128][64];
  __shared__ __align__(16) unsigned short Bs[2][128][64];
  const int t = threadIdx.x, l = t & 63, w = t >> 6;
  const int lr = l & 15, lg = l >> 4;
  const int wr = w >> 1, wc = w & 1;
  const int bid = blockIdx.x;
  const int swz = (bid & 7) * 128 + (bid >> 3);  // bijective XCD swizzle (1024 % 8 == 0)
  const int tn = swz & 3, tm = swz >> 2;

  const unsigned short* Bbase = (MODE == 3) ? (Bmat + (size_t)(tm >> 5) * 262144) : Bmat;
  // staging: lane l covers LDS row (l>>3), phys 16B-unit (l&7); global source
  // pre-swizzled so phys unit p holds logical unit p^(row&7)  [G21]
  const int r0 = w * 8 + (l >> 3);
  const int su = ((l & 7) ^ (l >> 3)) * 8;
  const unsigned short* Ag = A + (size_t)(tm * 128 + r0) * 512 + su;
  const unsigned short* Bg = Bbase + (size_t)(tn * 128 + r0) * 512 + su;

  f32x4 acc[4][4] = {};

#define PSTAGE(buf, kt)                                                        \
  {                                                                            \
    _Pragma("unroll") for (int i = 0; i < 4; ++i) {                            \
      gload16(Ag + (size_t)i * 32 * 512 + (kt) * 64, &As[buf][i * 32 + w * 8][0]); \
      gload16(Bg + (size_t)i * 32 * 512 + (kt) * 64, &Bs[buf][i * 32 + w * 8][0]); \
    }                                                                          \
  }

  PSTAGE(0, 0)
  PSTAGE(1, 1)
  for (int kt = 0; kt < 8; ++kt) {
    const int cur = kt & 1;
    if (kt < 7) { asm volatile("s_waitcnt vmcnt(8)" ::: "memory"); }
    else        { asm volatile("s_waitcnt vmcnt(0)" ::: "memory"); }
    __builtin_amdgcn_s_barrier();
    asm volatile("" ::: "memory");
    __builtin_amdgcn_s_setprio(1);
#pragma unroll
    for (int kk = 0; kk < 2; ++kk) {
      short8 af[4], bf[4];
#pragma unroll
      for (int m = 0; m < 4; ++m)
        af[m] = *(const short8*)&As[cur][wr * 64 + m * 16 + lr][((kk * 4 + lg) ^ (lr & 7)) * 8];
#pragma unroll
      for (int n = 0; n < 4; ++n)
        bf[n] = *(const short8*)&Bs[cur][wc * 64 + n * 16 + lr][((kk * 4 + lg) ^ (lr & 7)) * 8];
#pragma unroll
      for (int m = 0; m < 4; ++m)
#pragma unroll
        for (int n = 0; n < 4; ++n)
          acc[m][n] = __builtin_amdgcn_mfma_f32_16x16x32_bf16(af[m], bf[n], acc[m][n], 0, 0, 0);
    }
    __builtin_amdgcn_s_setprio(0);
    asm volatile("" ::: "memory");
    __builtin_amdgcn_s_barrier();
    asm volatile("" ::: "memory");
    if (kt < 6) PSTAGE(cur, kt + 2)
  }
#undef PSTAGE

  // ---- epilogue ----
  const int c_base = tn * 128 + wc * 64;
  const int r_base = tm * 128 + wr * 64;
  float bv_[4];
#pragma unroll
  for (int n = 0; n < 4; ++n) bv_[n] = bias[c_base + n * 16 + lr];

  if (MODE == 1) {
    unsigned short* Out = (unsigned short*)OutV;
    // fused query-softmax over this wave's 64 cols (= one head), fp32 in-register
#pragma unroll
    for (int m = 0; m < 4; ++m) {
#pragma unroll
      for (int j = 0; j < 4; ++j) {
        float a0 = acc[m][0][j] + bv_[0], a1 = acc[m][1][j] + bv_[1];
        float a2 = acc[m][2][j] + bv_[2], a3 = acc[m][3][j] + bv_[3];
        float mx = fmaxf(fmaxf(a0, a1), fmaxf(a2, a3));
#pragma unroll
        for (int o = 1; o < 16; o <<= 1) mx = fmaxf(mx, __shfl_xor(mx, o));
        float e0 = __expf(a0 - mx), e1 = __expf(a1 - mx);
        float e2 = __expf(a2 - mx), e3 = __expf(a3 - mx);
        float s = e0 + e1 + e2 + e3;
#pragma unroll
        for (int o = 1; o < 16; o <<= 1) s += __shfl_xor(s, o);
        const float rs = 1.0f / s;
        const int row = r_base + m * 16 + lg * 4 + j;
        Out[(size_t)row * 512 + c_base + 0 * 16 + lr] = f2bf(e0 * rs);
        Out[(size_t)row * 512 + c_base + 1 * 16 + lr] = f2bf(e1 * rs);
        Out[(size_t)row * 512 + c_base + 2 * 16 + lr] = f2bf(e2 * rs);
        Out[(size_t)row * 512 + c_base + 3 * 16 + lr] = f2bf(e3 * rs);
      }
    }
  } else if (MODE == 3) {
    float* Out = (float*)OutV;
#pragma unroll
    for (int n = 0; n < 4; ++n) {
      const int col = c_base + n * 16 + lr;
#pragma unroll
      for (int m = 0; m < 4; ++m) {
        const int row = r_base + m * 16 + lg * 4;
#pragma unroll
        for (int j = 0; j < 4; ++j)
          Out[(size_t)(row + j) * 512 + col] = acc[m][n][j] + bv_[n];
      }
    }
  } else if (MODE == 0) {
    unsigned short* Out = (unsigned short*)OutV;
    const int b = (tm * 128) >> 12;  // tile rows never cross a batch
#pragma unroll
    for (int n = 0; n < 4; ++n) {
      const int col = c_base + n * 16 + lr;
      float srow = 0.f;
#pragma unroll
      for (int m = 0; m < 4; ++m) {
        const int row = r_base + m * 16 + lg * 4;
        const int nl = row & 4095;
        us4 v;
#pragma unroll
        for (int j = 0; j < 4; ++j) {
          float f = __expf(acc[m][n][j] + bv_[n]);
          srow += f;
          v[j] = f2bf(f);
        }
        *(us4*)&Out[((size_t)(b * 512 + col)) * 4096 + nl] = v;
      }
      // reduce over the 4 lg groups (lanes differing in bits 4,5), 1 atomic/col/wave
      srow += __shfl_xor(srow, 16);
      srow += __shfl_xor(srow, 32);
      if (lg == 0) atomicAdd(&S[b * 512 + col], srow);
    }
  } else {
    unsigned short* Out = (unsigned short*)OutV;
    const int b = (tm * 128) >> 12;
#pragma unroll
    for (int n = 0; n < 4; ++n) {
      const int col = c_base + n * 16 + lr;
#pragma unroll
      for (int m = 0; m < 4; ++m) {
        const int row = r_base + m * 16 + lg * 4;
        const int nl = row & 4095;
        us4 v;
#pragma unroll
        for (int j = 0; j < 4; ++j) v[j] = f2bf(acc[m][n][j] + bv_[n]);
        *(us4*)&Out[((size_t)(b * 512 + col)) * 4096 + nl] = v;
      }
    }
  }
}

// ---------------------------------------------------------------------------
// Partial context: D[v][k] = sum_tok VT[v][tok] * KeT[k][tok] over a 1024-token chunk.
__global__ void context_partial(const unsigned short* __restrict__ KeT,
                                const unsigned short* __restrict__ VT,
                                float* __restrict__ cp) {
  const int t = threadIdx.x, l = t & 63, w = t >> 6;
  const int lr = l & 15, lg = l >> 4;
  const int ch = blockIdx.x, h = blockIdx.y, b = blockIdx.z;
  const unsigned short* Kp = KeT + ((size_t)b * 512 + h * 64) * 4096;
  const unsigned short* Vp = VT + ((size_t)b * 512 + h * 64) * 4096;
  const int tok_w = ch * 1024 + w * 256;
  f32x4 acc[4][4] = {};
  for (int s = 0; s < 8; ++s) {
    const int tok = tok_w + s * 32 + lg * 8;
    short8 a[4], kf[4];
#pragma unroll
    for (int m = 0; m < 4; ++m) a[m] = *(const short8*)&Vp[(size_t)(m * 16 + lr) * 4096 + tok];
#pragma unroll
    for (int n = 0; n < 4; ++n) kf[n] = *(const short8*)&Kp[(size_t)(n * 16 + lr) * 4096 + tok];
#pragma unroll
    for (int m = 0; m < 4; ++m)
#pragma unroll
      for (int n = 0; n < 4; ++n)
        acc[m][n] = __builtin_amdgcn_mfma_f32_16x16x32_bf16(a[m], kf[n], acc[m][n], 0, 0, 0);
  }
  __shared__ float red[4][64][64];
#pragma unroll
  for (int m = 0; m < 4; ++m)
#pragma unroll
    for (int n = 0; n < 4; ++n)
#pragma unroll
      for (int j = 0; j < 4; ++j)
        red[w][m * 16 + lg * 4 + j][n * 16 + lr] = acc[m][n][j];
  __syncthreads();
  const int blk = (b * 8 + h) * 4 + ch;
  float* o = cp + (size_t)blk * 4096;
  for (int i = 0; i < 16; ++i) {
    int e = i * 256 + t;
    int v = e >> 6, k = e & 63;
    o[e] = red[0][v][k] + red[1][v][k] + red[2][v][k] + red[3][v][k];
  }
}

// ---------------------------------------------------------------------------
// Fused ctx_reduce + ctx_mm: per block (cc,h,b):
//   ctx[k][v] = (sum_ch cp[bh][ch][v*64+k]) / S[bh*64+k]   (into padded LDS)
//   MT[b][c][h*64+k] = sum_v ctx[k][v] * Wrt[c][h*64+v]    for c in cc*128+[0,128)
__global__ __launch_bounds__(256) void ctx_mm2(const float* __restrict__ cp,
                      const float* __restrict__ S, const unsigned short* __restrict__ Wrt,
                      unsigned short* __restrict__ MT) {
  __shared__ __align__(16) unsigned short ctx_lds[64][72];  // +8 pad: 2-way-free reads
  const int t = threadIdx.x, l = t & 63, w = t >> 6;
  const int lr = l & 15, lg = l >> 4;
  const int cc = blockIdx.x, h = blockIdx.y, b = blockIdx.z;
  const int bh = b * 8 + h;

  // reduce 4 chunk-partials + normalize -> LDS (thread: fixed k, 16 v's)
  const int k = t & 63, vg = t >> 6;
  const float rs = 1.0f / S[bh * 64 + k];
  const float* pb = cp + (size_t)bh * 4 * 4096 + k;
#pragma unroll
  for (int half = 0; half < 2; ++half) {
    short8 pkv;
#pragma unroll
    for (int i = 0; i < 8; ++i) {
      const int v = vg * 16 + half * 8 + i;
      const size_t e = (size_t)v * 64;
      float vsum = pb[e] + pb[4096 + e] + pb[8192 + e] + pb[12288 + e];
      pkv[i] = (short)f2bf(vsum * rs);
    }
    *(short8*)&ctx_lds[k][vg * 16 + half * 8] = pkv;
  }
  __syncthreads();

  const int c0 = cc * 128 + w * 32;
  f32x4 acc[4][2] = {};
#pragma unroll
  for (int kk = 0; kk < 2; ++kk) {
    const int vb = kk * 32 + lg * 8;
    short8 a[4], bfr[2];
#pragma unroll
    for (int m = 0; m < 4; ++m) a[m] = *(const short8*)&ctx_lds[m * 16 + lr][vb];
#pragma unroll
    for (int n = 0; n < 2; ++n)
      bfr[n] = *(const short8*)&Wrt[(size_t)(c0 + n * 16 + lr) * 512 + h * 64 + vb];
#pragma unroll
    for (int m = 0; m < 4; ++m)
#pragma unroll
      for (int n = 0; n < 2; ++n)
        acc[m][n] = __builtin_amdgcn_mfma_f32_16x16x32_bf16(a[m], bfr[n], acc[m][n], 0, 0, 0);
  }
#pragma unroll
  for (int n = 0; n < 2; ++n) {
    const int c = c0 + n * 16 + lr;
#pragma unroll
    for (int m = 0; m < 4; ++m) {
      const int kq = m * 16 + lg * 4;
      us4 v;
#pragma unroll
      for (int j = 0; j < 4; ++j) v[j] = f2bf(acc[m][n][j]);
      *(us4*)&MT[((size_t)b * 512 + c) * 512 + h * 64 + kq] = v;
    }
  }
}

// ---------------------------------------------------------------------------
extern "C" void kernel_launch(void* const* d_in, const int* in_sizes, int n_in,
                              void* d_out, int out_size, void* d_ws, size_t ws_size,
                              hipStream_t stream) {
  (void)in_sizes; (void)n_in; (void)out_size; (void)ws_size;
  const float* x  = (const float*)d_in[0];
  const float* y  = (const float*)d_in[1];
  const float* Wk = (const float*)d_in[2];
  const float* bk = (const float*)d_in[3];
  const float* Wq = (const float*)d_in[4];
  const float* bq = (const float*)d_in[5];
  const float* Wv = (const float*)d_in[6];
  const float* bv = (const float*)d_in[7];
  const float* Wr = (const float*)d_in[8];
  const float* br = (const float*)d_in[9];
  float* out = (float*)d_out;

  char* ws = (char*)d_ws;
  unsigned short* Wt   = (unsigned short*)(ws + 0);            //   2 MB: 4x [512][512] bf16
  unsigned short* xb   = (unsigned short*)(ws + 2097152);      //  32 MB: bf16(x)
  unsigned short* yb   = (unsigned short*)(ws + 35651584);     //  32 MB: bf16(y)
  unsigned short* xyb  = (unsigned short*)(ws + 69206016);     //  32 MB: bf16(x+y); reused as Qp
  unsigned short* KeT  = (unsigned short*)(ws + 102760448);    //  32 MB: [B][512][4096] bf16
  unsigned short* VT   = (unsigned short*)(ws + 136314880);    //  32 MB: [B][512][4096] bf16
  float* S             = (float*)(ws + 169869312);             //  16 KB
  float* cp            = (float*)(ws + 169885696);             //   4 MB
  unsigned short* MT   = (unsigned short*)(ws + 174080000);    //   4 MB (ends ~178.3 MB)
  unsigned short* Qp   = xyb;                                  // xyb dead after gemm<0>

  prep_w<<<dim3(8, 8, 4), 256, 0, stream>>>(Wk, Wq, Wv, Wr, Wt);
  prep_xy<<<8192, 256, 0, stream>>>(x, y, xb, yb, xyb);
  hipMemsetAsync(S, 0, 512 * 8 * sizeof(float), stream);
  gemm_bf16<0><<<1024, 256, 0, stream>>>(xyb, Wt, bk, KeT, S);
  gemm_bf16<2><<<1024, 256, 0, stream>>>(xb, Wt + 2 * 262144, bv, VT, nullptr);
  gemm_bf16<1><<<1024, 256, 0, stream>>>(yb, Wt + 262144, bq, Qp, nullptr);
  context_partial<<<dim3(4, 8, 8), 256, 0, stream>>>(KeT, VT, cp);
  ctx_mm2<<<dim3(4, 8, 8), 256, 0, stream>>>(cp, S, Wt + 3 * 262144, MT);
  gemm_bf16<3><<<1024, 256, 0, stream>>>(Qp, MT, br, out, nullptr);
}

// Round 10
// 186.480 us; speedup vs baseline: 1.5479x; 1.0065x over previous
//
#include <hip/hip_runtime.h>
#include <hip/hip_bf16.h>
#include <stdint.h>

// Problem constants: B=8, N=4096, C=512, K=V=512, H=8, hk=hv=64, M = B*N = 32768

typedef __attribute__((ext_vector_type(8))) short short8;
typedef __attribute__((ext_vector_type(4))) float f32x4;
typedef __attribute__((ext_vector_type(4))) unsigned short us4;

__device__ __forceinline__ unsigned short f2bf(float f) {
  union { float f; unsigned u; } v; v.f = f;
  unsigned r = v.u + 0x7FFFu + ((v.u >> 16) & 1u);  // RNE
  return (unsigned short)(r >> 16);
}
__device__ __forceinline__ float bf2f(unsigned short u) {
  union { unsigned u; float f; } v; v.u = ((unsigned)u) << 16;
  return v.f;
}
__device__ __forceinline__ ushort2 pk2(float a, float b) {
  __hip_bfloat162 h = __float22bfloat162_rn(float2{a, b});
  return *reinterpret_cast<ushort2*>(&h);
}
__device__ __forceinline__ us4 cvt4(float4 a) {
  ushort2 c0 = pk2(a.x, a.y), c1 = pk2(a.z, a.w);
  us4 r; r[0] = c0.x; r[1] = c0.y; r[2] = c1.x; r[3] = c1.y;
  return r;
}
// async global->LDS, 16B per lane; lds base wave-uniform (HW: base + lane*16)
__device__ __forceinline__ void gload16(const void* g, void* l) {
  __builtin_amdgcn_global_load_lds(
      (const __attribute__((address_space(1))) void*)g,
      (__attribute__((address_space(3))) void*)l, 16, 0, 0);
}

// ---------------------------------------------------------------------------
// Transpose + bf16-convert the 4 weight matrices: Wt[w][out][in] = W[in][out].
// Block (0,0,3) additionally zeroes S (16 KB) — saves a memset dispatch;
// ordering to gemm<0>'s atomics is guaranteed by dispatch serialization.
__global__ void prep_w(const float* __restrict__ Wk, const float* __restrict__ Wq,
                       const float* __restrict__ Wv, const float* __restrict__ Wr,
                       unsigned short* __restrict__ Wt, float* __restrict__ S) {
  __shared__ float tile[64][65];
  const int t = threadIdx.x;
  const int bx = blockIdx.x, by = blockIdx.y, w = blockIdx.z;
  if (w == 3 && bx == 0 && by == 0) {
#pragma unroll
    for (int i = 0; i < 16; ++i) S[i * 256 + t] = 0.f;
  }
  const float* W = (w == 0) ? Wk : (w == 1) ? Wq : (w == 2) ? Wv : Wr;
  unsigned short* O = Wt + (size_t)w * 512 * 512;
#pragma unroll
  for (int p = 0; p < 16; ++p) {
    int idx = p * 256 + t; int r = idx >> 6, c = idx & 63;
    tile[r][c] = W[(size_t)(by * 64 + r) * 512 + bx * 64 + c];
  }
  __syncthreads();
#pragma unroll
  for (int p = 0; p < 16; ++p) {
    int idx = p * 256 + t; int r = idx >> 6, c = idx & 63;
    O[(size_t)(bx * 64 + r) * 512 + by * 64 + c] = f2bf(tile[c][r]);
  }
}

// ---------------------------------------------------------------------------
// Streaming pre-pass: xb=bf16(x), yb=bf16(y), xyb=bf16(x+y).
// Max-TLP: 1 float4 per stream per thread (2 loads, 3 stores, short dep chain),
// 16384 blocks = 4096 waves = 16 waves/CU.
__global__ __launch_bounds__(256) void prep_xy(const float* __restrict__ x, const float* __restrict__ y,
                        unsigned short* __restrict__ xb, unsigned short* __restrict__ yb,
                        unsigned short* __restrict__ xyb) {
  const size_t i = ((size_t)blockIdx.x * 256 + threadIdx.x) * 4;
  float4 a = *(const float4*)(x + i);
  float4 b = *(const float4*)(y + i);
  float4 s{a.x + b.x, a.y + b.y, a.z + b.z, a.w + b.w};
  *(us4*)(xb + i) = cvt4(a);
  *(us4*)(yb + i) = cvt4(b);
  *(us4*)(xyb + i) = cvt4(s);
}

// ---------------------------------------------------------------------------
// bf16 GEMM (R5 skeleton, proven ~25us): 128x128 tile, BK=64, double-buffered
// LDS, counted vmcnt (never 0 mid-loop), raw s_barrier, XOR-swizzled LDS
// (linear gload dest + pre-swizzled global src, swizzled ds_read).
// MODE 0: epilogue exp(), TRANSPOSED out (KeT[b][k][tok]) + S atomic row-sums
// MODE 1: epilogue fused head-softmax (64 ch), row-major bf16 out
// MODE 2: plain, TRANSPOSED out (VT[b][v][tok], bf16)
// MODE 3: final: B = Bmat + batch*512*512, fp32 row-major out + bias
template <int MODE>
__global__ __launch_bounds__(256) void gemm_bf16(const unsigned short* __restrict__ A,
                          const unsigned short* __restrict__ Bmat,
                          const float* __restrict__ bias, void* __restrict__ OutV,
                          float* __restrict__ S) {
  __shared__ __align__(16) unsigned short As[2][128][64];
  __shared__ __align__(16) unsigned short Bs[2][128][64];
  const int t = threadIdx.x, l = t & 63, w = t >> 6;
  const int lr = l & 15, lg = l >> 4;
  const int wr = w >> 1, wc = w & 1;
  const int bid = blockIdx.x;
  const int swz = (bid & 7) * 128 + (bid >> 3);  // bijective XCD swizzle (1024 % 8 == 0)
  const int tn = swz & 3, tm = swz >> 2;

  const unsigned short* Bbase = (MODE == 3) ? (Bmat + (size_t)(tm >> 5) * 262144) : Bmat;
  // staging: lane l covers LDS row (l>>3), phys 16B-unit (l&7); global source
  // pre-swizzled so phys unit p holds logical unit p^(row&7)  [G21]
  const int r0 = w * 8 + (l >> 3);
  const int su = ((l & 7) ^ (l >> 3)) * 8;
  const unsigned short* Ag = A + (size_t)(tm * 128 + r0) * 512 + su;
  const unsigned short* Bg = Bbase + (size_t)(tn * 128 + r0) * 512 + su;

  f32x4 acc[4][4] = {};

#define PSTAGE(buf, kt)                                                        \
  {                                                                            \
    _Pragma("unroll") for (int i = 0; i < 4; ++i) {                            \
      gload16(Ag + (size_t)i * 32 * 512 + (kt) * 64, &As[buf][i * 32 + w * 8][0]); \
      gload16(Bg + (size_t)i * 32 * 512 + (kt) * 64, &Bs[buf][i * 32 + w * 8][0]); \
    }                                                                          \
  }

  PSTAGE(0, 0)
  PSTAGE(1, 1)
  for (int kt = 0; kt < 8; ++kt) {
    const int cur = kt & 1;
    if (kt < 7) { asm volatile("s_waitcnt vmcnt(8)" ::: "memory"); }
    else        { asm volatile("s_waitcnt vmcnt(0)" ::: "memory"); }
    __builtin_amdgcn_s_barrier();
    asm volatile("" ::: "memory");
    __builtin_amdgcn_s_setprio(1);
#pragma unroll
    for (int kk = 0; kk < 2; ++kk) {
      short8 af[4], bf[4];
#pragma unroll
      for (int m = 0; m < 4; ++m)
        af[m] = *(const short8*)&As[cur][wr * 64 + m * 16 + lr][((kk * 4 + lg) ^ (lr & 7)) * 8];
#pragma unroll
      for (int n = 0; n < 4; ++n)
        bf[n] = *(const short8*)&Bs[cur][wc * 64 + n * 16 + lr][((kk * 4 + lg) ^ (lr & 7)) * 8];
#pragma unroll
      for (int m = 0; m < 4; ++m)
#pragma unroll
        for (int n = 0; n < 4; ++n)
          acc[m][n] = __builtin_amdgcn_mfma_f32_16x16x32_bf16(af[m], bf[n], acc[m][n], 0, 0, 0);
    }
    __builtin_amdgcn_s_setprio(0);
    asm volatile("" ::: "memory");
    __builtin_amdgcn_s_barrier();
    asm volatile("" ::: "memory");
    if (kt < 6) PSTAGE(cur, kt + 2)
  }
#undef PSTAGE

  // ---- epilogue ----
  const int c_base = tn * 128 + wc * 64;
  const int r_base = tm * 128 + wr * 64;
  float bv_[4];
#pragma unroll
  for (int n = 0; n < 4; ++n) bv_[n] = bias[c_base + n * 16 + lr];

  if (MODE == 1) {
    unsigned short* Out = (unsigned short*)OutV;
    // fused query-softmax over this wave's 64 cols (= one head), fp32 in-register
#pragma unroll
    for (int m = 0; m < 4; ++m) {
#pragma unroll
      for (int j = 0; j < 4; ++j) {
        float a0 = acc[m][0][j] + bv_[0], a1 = acc[m][1][j] + bv_[1];
        float a2 = acc[m][2][j] + bv_[2], a3 = acc[m][3][j] + bv_[3];
        float mx = fmaxf(fmaxf(a0, a1), fmaxf(a2, a3));
#pragma unroll
        for (int o = 1; o < 16; o <<= 1) mx = fmaxf(mx, __shfl_xor(mx, o));
        float e0 = __expf(a0 - mx), e1 = __expf(a1 - mx);
        float e2 = __expf(a2 - mx), e3 = __expf(a3 - mx);
        float s = e0 + e1 + e2 + e3;
#pragma unroll
        for (int o = 1; o < 16; o <<= 1) s += __shfl_xor(s, o);
        const float rs = 1.0f / s;
        const int row = r_base + m * 16 + lg * 4 + j;
        Out[(size_t)row * 512 + c_base + 0 * 16 + lr] = f2bf(e0 * rs);
        Out[(size_t)row * 512 + c_base + 1 * 16 + lr] = f2bf(e1 * rs);
        Out[(size_t)row * 512 + c_base + 2 * 16 + lr] = f2bf(e2 * rs);
        Out[(size_t)row * 512 + c_base + 3 * 16 + lr] = f2bf(e3 * rs);
      }
    }
  } else if (MODE == 3) {
    float* Out = (float*)OutV;
#pragma unroll
    for (int n = 0; n < 4; ++n) {
      const int col = c_base + n * 16 + lr;
#pragma unroll
      for (int m = 0; m < 4; ++m) {
        const int row = r_base + m * 16 + lg * 4;
#pragma unroll
        for (int j = 0; j < 4; ++j)
          Out[(size_t)(row + j) * 512 + col] = acc[m][n][j] + bv_[n];
      }
    }
  } else if (MODE == 0) {
    unsigned short* Out = (unsigned short*)OutV;
    const int b = (tm * 128) >> 12;  // tile rows never cross a batch
#pragma unroll
    for (int n = 0; n < 4; ++n) {
      const int col = c_base + n * 16 + lr;
      float srow = 0.f;
#pragma unroll
      for (int m = 0; m < 4; ++m) {
        const int row = r_base + m * 16 + lg * 4;
        const int nl = row & 4095;
        us4 v;
#pragma unroll
        for (int j = 0; j < 4; ++j) {
          float f = __expf(acc[m][n][j] + bv_[n]);
          srow += f;
          v[j] = f2bf(f);
        }
        *(us4*)&Out[((size_t)(b * 512 + col)) * 4096 + nl] = v;
      }
      // reduce over the 4 lg groups (lanes differing in bits 4,5), 1 atomic/col/wave
      srow += __shfl_xor(srow, 16);
      srow += __shfl_xor(srow, 32);
      if (lg == 0) atomicAdd(&S[b * 512 + col], srow);
    }
  } else {
    unsigned short* Out = (unsigned short*)OutV;
    const int b = (tm * 128) >> 12;
#pragma unroll
    for (int n = 0; n < 4; ++n) {
      const int col = c_base + n * 16 + lr;
#pragma unroll
      for (int m = 0; m < 4; ++m) {
        const int row = r_base + m * 16 + lg * 4;
        const int nl = row & 4095;
        us4 v;
#pragma unroll
        for (int j = 0; j < 4; ++j) v[j] = f2bf(acc[m][n][j] + bv_[n]);
        *(us4*)&Out[((size_t)(b * 512 + col)) * 4096 + nl] = v;
      }
    }
  }
}

// ---------------------------------------------------------------------------
// Partial context: D[v][k] = sum_tok VT[v][tok] * KeT[k][tok] over a 1024-token chunk.
__global__ void context_partial(const unsigned short* __restrict__ KeT,
                                const unsigned short* __restrict__ VT,
                                float* __restrict__ cp) {
  const int t = threadIdx.x, l = t & 63, w = t >> 6;
  const int lr = l & 15, lg = l >> 4;
  const int ch = blockIdx.x, h = blockIdx.y, b = blockIdx.z;
  const unsigned short* Kp = KeT + ((size_t)b * 512 + h * 64) * 4096;
  const unsigned short* Vp = VT + ((size_t)b * 512 + h * 64) * 4096;
  const int tok_w = ch * 1024 + w * 256;
  f32x4 acc[4][4] = {};
  for (int s = 0; s < 8; ++s) {
    const int tok = tok_w + s * 32 + lg * 8;
    short8 a[4], kf[4];
#pragma unroll
    for (int m = 0; m < 4; ++m) a[m] = *(const short8*)&Vp[(size_t)(m * 16 + lr) * 4096 + tok];
#pragma unroll
    for (int n = 0; n < 4; ++n) kf[n] = *(const short8*)&Kp[(size_t)(n * 16 + lr) * 4096 + tok];
#pragma unroll
    for (int m = 0; m < 4; ++m)
#pragma unroll
      for (int n = 0; n < 4; ++n)
        acc[m][n] = __builtin_amdgcn_mfma_f32_16x16x32_bf16(a[m], kf[n], acc[m][n], 0, 0, 0);
  }
  __shared__ float red[4][64][64];
#pragma unroll
  for (int m = 0; m < 4; ++m)
#pragma unroll
    for (int n = 0; n < 4; ++n)
#pragma unroll
      for (int j = 0; j < 4; ++j)
        red[w][m * 16 + lg * 4 + j][n * 16 + lr] = acc[m][n][j];
  __syncthreads();
  const int blk = (b * 8 + h) * 4 + ch;
  float* o = cp + (size_t)blk * 4096;
  for (int i = 0; i < 16; ++i) {
    int e = i * 256 + t;
    int v = e >> 6, k = e & 63;
    o[e] = red[0][v][k] + red[1][v][k] + red[2][v][k] + red[3][v][k];
  }
}

// ---------------------------------------------------------------------------
// Fused ctx_reduce + ctx_mm: per block (cc,h,b):
//   ctx[k][v] = (sum_ch cp[bh][ch][v*64+k]) / S[bh*64+k]   (into padded LDS)
//   MT[b][c][h*64+k] = sum_v ctx[k][v] * Wrt[c][h*64+v]    for c in cc*128+[0,128)
__global__ __launch_bounds__(256) void ctx_mm2(const float* __restrict__ cp,
                      const float* __restrict__ S, const unsigned short* __restrict__ Wrt,
                      unsigned short* __restrict__ MT) {
  __shared__ __align__(16) unsigned short ctx_lds[64][72];  // +8 pad: 2-way-free reads
  const int t = threadIdx.x, l = t & 63, w = t >> 6;
  const int lr = l & 15, lg = l >> 4;
  const int cc = blockIdx.x, h = blockIdx.y, b = blockIdx.z;
  const int bh = b * 8 + h;

  // reduce 4 chunk-partials + normalize -> LDS (thread: fixed k, 16 v's)
  const int k = t & 63, vg = t >> 6;
  const float rs = 1.0f / S[bh * 64 + k];
  const float* pb = cp + (size_t)bh * 4 * 4096 + k;
#pragma unroll
  for (int half = 0; half < 2; ++half) {
    short8 pkv;
#pragma unroll
    for (int i = 0; i < 8; ++i) {
      const int v = vg * 16 + half * 8 + i;
      const size_t e = (size_t)v * 64;
      float vsum = pb[e] + pb[4096 + e] + pb[8192 + e] + pb[12288 + e];
      pkv[i] = (short)f2bf(vsum * rs);
    }
    *(short8*)&ctx_lds[k][vg * 16 + half * 8] = pkv;
  }
  __syncthreads();

  const int c0 = cc * 128 + w * 32;
  f32x4 acc[4][2] = {};
#pragma unroll
  for (int kk = 0; kk < 2; ++kk) {
    const int vb = kk * 32 + lg * 8;
    short8 a[4], bfr[2];
#pragma unroll
    for (int m = 0; m < 4; ++m) a[m] = *(const short8*)&ctx_lds[m * 16 + lr][vb];
#pragma unroll
    for (int n = 0; n < 2; ++n)
      bfr[n] = *(const short8*)&Wrt[(size_t)(c0 + n * 16 + lr) * 512 + h * 64 + vb];
#pragma unroll
    for (int m = 0; m < 4; ++m)
#pragma unroll
      for (int n = 0; n < 2; ++n)
        acc[m][n] = __builtin_amdgcn_mfma_f32_16x16x32_bf16(a[m], bfr[n], acc[m][n], 0, 0, 0);
  }
#pragma unroll
  for (int n = 0; n < 2; ++n) {
    const int c = c0 + n * 16 + lr;
#pragma unroll
    for (int m = 0; m < 4; ++m) {
      const int kq = m * 16 + lg * 4;
      us4 v;
#pragma unroll
      for (int j = 0; j < 4; ++j) v[j] = f2bf(acc[m][n][j]);
      *(us4*)&MT[((size_t)b * 512 + c) * 512 + h * 64 + kq] = v;
    }
  }
}

// ---------------------------------------------------------------------------
extern "C" void kernel_launch(void* const* d_in, const int* in_sizes, int n_in,
                              void* d_out, int out_size, void* d_ws, size_t ws_size,
                              hipStream_t stream) {
  (void)in_sizes; (void)n_in; (void)out_size; (void)ws_size;
  const float* x  = (const float*)d_in[0];
  const float* y  = (const float*)d_in[1];
  const float* Wk = (const float*)d_in[2];
  const float* bk = (const float*)d_in[3];
  const float* Wq = (const float*)d_in[4];
  const float* bq = (const float*)d_in[5];
  const float* Wv = (const float*)d_in[6];
  const float* bv = (const float*)d_in[7];
  const float* Wr = (const float*)d_in[8];
  const float* br = (const float*)d_in[9];
  float* out = (float*)d_out;

  char* ws = (char*)d_ws;
  unsigned short* Wt   = (unsigned short*)(ws + 0);            //   2 MB: 4x [512][512] bf16
  unsigned short* xb   = (unsigned short*)(ws + 2097152);      //  32 MB: bf16(x)
  unsigned short* yb   = (unsigned short*)(ws + 35651584);     //  32 MB: bf16(y)
  unsigned short* xyb  = (unsigned short*)(ws + 69206016);     //  32 MB: bf16(x+y); reused as Qp
  unsigned short* KeT  = (unsigned short*)(ws + 102760448);    //  32 MB: [B][512][4096] bf16
  unsigned short* VT   = (unsigned short*)(ws + 136314880);    //  32 MB: [B][512][4096] bf16
  float* S             = (float*)(ws + 169869312);             //  16 KB
  float* cp            = (float*)(ws + 169885696);             //   4 MB
  unsigned short* MT   = (unsigned short*)(ws + 174080000);    //   4 MB (ends ~178.3 MB)
  unsigned short* Qp   = xyb;                                  // xyb dead after gemm<0>

  prep_w<<<dim3(8, 8, 4), 256, 0, stream>>>(Wk, Wq, Wv, Wr, Wt, S);
  prep_xy<<<16384, 256, 0, stream>>>(x, y, xb, yb, xyb);
  gemm_bf16<0><<<1024, 256, 0, stream>>>(xyb, Wt, bk, KeT, S);
  gemm_bf16<2><<<1024, 256, 0, stream>>>(xb, Wt + 2 * 262144, bv, VT, nullptr);
  gemm_bf16<1><<<1024, 256, 0, stream>>>(yb, Wt + 262144, bq, Qp, nullptr);
  context_partial<<<dim3(4, 8, 8), 256, 0, stream>>>(KeT, VT, cp);
  ctx_mm2<<<dim3(4, 8, 8), 256, 0, stream>>>(cp, S, Wt + 3 * 262144, MT);
  gemm_bf16<3><<<1024, 256, 0, stream>>>(Qp, MT, br, out, nullptr);
}